// Round 1
// baseline (612.672 us; speedup 1.0000x reference)
//
#include <hip/hip_runtime.h>
#include <hip/hip_bf16.h>
#include <stdint.h>

// BERT self-attention fwd: B=4,S=2048,H=1024,NH=16,HD=64. fp32 in/out, bf16 MFMA compute.
// ws layout: Xb bf16[8192][1024] @0 (16MB) | Wt bf16[3072][1024] @16MB (6MB)
//            Qb bf16[64][2048][64] @22MB | Kb @38MB | Vt bf16[64][64][2048] @54MB

typedef unsigned short ushort_t;
typedef __attribute__((ext_vector_type(4))) float f32x4;
typedef __attribute__((ext_vector_type(8))) short short8;

#define MFMA16(a, b, c) __builtin_amdgcn_mfma_f32_16x16x32_bf16((a), (b), (c), 0, 0, 0)

__device__ __forceinline__ ushort_t f2bf(float f) {
  unsigned u = __float_as_uint(f);
  u = (u + 0x7FFFu + ((u >> 16) & 1u)) >> 16;
  return (ushort_t)u;
}

typedef __attribute__((address_space(1))) unsigned int as1_uint;
typedef __attribute__((address_space(3))) unsigned int as3_uint;

// async global->LDS, 16B per lane; lds_dst must be wave-uniform base (lane writes base + lane*16)
__device__ __forceinline__ void async16(void* lds_dst, const void* g_src) {
  __builtin_amdgcn_global_load_lds((as1_uint*)(uintptr_t)g_src,
                                   (as3_uint*)(unsigned)(uintptr_t)lds_dst, 16, 0, 0);
}

// ---------------- convert X fp32 -> bf16 ----------------
__global__ __launch_bounds__(256) void convert_x(const float* __restrict__ X,
                                                 ushort_t* __restrict__ Xb) {
  int idx = (blockIdx.x * 256 + threadIdx.x) * 8;
  f32x4 a = *(const f32x4*)(X + idx);
  f32x4 b = *(const f32x4*)(X + idx + 4);
  short8 r;
#pragma unroll
  for (int j = 0; j < 4; ++j) r[j] = (short)f2bf(a[j]);
#pragma unroll
  for (int j = 0; j < 4; ++j) r[4 + j] = (short)f2bf(b[j]);
  *(short8*)(Xb + idx) = r;
}

// ---------------- convert + transpose W -> Wt[n][k] bf16, 3 mats stacked ----------------
__global__ __launch_bounds__(256) void convert_w(const float* __restrict__ Wq,
                                                 const float* __restrict__ Wk,
                                                 const float* __restrict__ Wv,
                                                 ushort_t* __restrict__ Wt) {
  const int mat = blockIdx.z;
  const float* W = (mat == 0) ? Wq : ((mat == 1) ? Wk : Wv);
  const int k0 = blockIdx.x * 64, n0 = blockIdx.y * 64;
  __shared__ float t[64][65];
  const int tid = threadIdx.x;
#pragma unroll
  for (int it = 0; it < 16; ++it) {
    int idx = it * 256 + tid;
    int r = idx >> 6, c = idx & 63;
    t[r][c] = W[(size_t)(k0 + r) * 1024 + n0 + c];
  }
  __syncthreads();
#pragma unroll
  for (int it = 0; it < 16; ++it) {
    int idx = it * 256 + tid;
    int nr = idx >> 6, kc = idx & 63;
    Wt[(size_t)(mat * 1024 + n0 + nr) * 1024 + k0 + kc] = f2bf(t[kc][nr]);
  }
}

// ---------------- fused QKV GEMM: C[8192][3072] = Xb @ W, epilogue scatters to Q/K/Vt ----------------
__global__ __launch_bounds__(256) void gemm_qkv(const ushort_t* __restrict__ Xb,
                                                const ushort_t* __restrict__ Wt,
                                                const float* __restrict__ bq,
                                                const float* __restrict__ bk,
                                                const float* __restrict__ bv,
                                                ushort_t* __restrict__ Qb,
                                                ushort_t* __restrict__ Kb,
                                                ushort_t* __restrict__ Vt) {
  __shared__ char lds[36864];  // A 16KB @0, B 16KB @16384; epilogue V-transpose 4*9216
  const int tid = threadIdx.x;
  const int l = tid & 63, w = tid >> 6;
  const int m0 = blockIdx.x * 128;
  const int n0 = blockIdx.y * 128;
  const int wm = w >> 1, wn = w & 1;

  // staging: lane l covers phys LDS byte l*16 of each 1KB chunk; row = chunk*8 + (l>>3)
  // swizzle: phys kb = logical kb ^ ((row&7)<<4); row&7 == l>>3 for staging rows
  const int lr = l >> 3;
  const int kb_log = (((l & 7) ^ lr) << 4);
  const char* srcA = (const char*)Xb + (size_t)(m0 + w * 32 + lr) * 2048 + kb_log;
  const char* srcB = (const char*)Wt + (size_t)(n0 + w * 32 + lr) * 2048 + kb_log;
  char* ldsA_w = lds + w * 4096;
  char* ldsB_w = lds + 16384 + w * 4096;

  // fragment read offsets (logical kb XOR row-swizzle; row&7 == l&7 for frag rows)
  const int ra = wm * 64 + (l & 15);
  const int rb = wn * 64 + (l & 15);
  const int swz = (l & 7) << 4;
  const int x0 = (((l >> 4) << 4)) ^ swz;
  const int x1 = (64 + ((l >> 4) << 4)) ^ swz;

  f32x4 acc[4][4];
#pragma unroll
  for (int mf = 0; mf < 4; ++mf)
#pragma unroll
    for (int nf = 0; nf < 4; ++nf) acc[mf][nf] = (f32x4){0.f, 0.f, 0.f, 0.f};

#pragma unroll 1
  for (int kt = 0; kt < 16; ++kt) {
    if (kt) __syncthreads();
    const int koff = kt * 128;
#pragma unroll
    for (int c = 0; c < 4; ++c) {
      async16(ldsA_w + c * 1024, srcA + c * 16384 + koff);
      async16(ldsB_w + c * 1024, srcB + c * 16384 + koff);
    }
    __syncthreads();
#pragma unroll
    for (int half = 0; half < 2; ++half) {
      const int xo = half ? x1 : x0;
      short8 av[4], bv2[4];
#pragma unroll
      for (int mf = 0; mf < 4; ++mf)
        av[mf] = *(const short8*)(lds + (ra + mf * 16) * 128 + xo);
#pragma unroll
      for (int nf = 0; nf < 4; ++nf)
        bv2[nf] = *(const short8*)(lds + 16384 + (rb + nf * 16) * 128 + xo);
#pragma unroll
      for (int mf = 0; mf < 4; ++mf)
#pragma unroll
        for (int nf = 0; nf < 4; ++nf)
          acc[mf][nf] = MFMA16(av[mf], bv2[nf], acc[mf][nf]);
    }
  }

  __syncthreads();
  // epilogue
  const int col0 = n0 + wn * 64;           // 64-aligned -> single (mat, head)
  const int mat = col0 >> 10;
  const int nn0 = col0 & 1023;
  const int hh = nn0 >> 6;
  const int row0 = m0 + wm * 64;
  const int bb = row0 >> 11;
  const int s0 = row0 & 2047;
  const float* bias = (mat == 0) ? bq : ((mat == 1) ? bk : bv);
  if (mat < 2) {
    ushort_t* dst = (mat == 0) ? Qb : Kb;
#pragma unroll
    for (int mf = 0; mf < 4; ++mf)
#pragma unroll
      for (int nf = 0; nf < 4; ++nf)
#pragma unroll
        for (int i = 0; i < 4; ++i) {
          int r = mf * 16 + (l >> 4) * 4 + i;
          int d = nf * 16 + (l & 15);
          float v = acc[mf][nf][i] + bias[nn0 + d];
          dst[((size_t)(bb * 16 + hh) * 2048 + (s0 + r)) * 64 + d] = f2bf(v);
        }
  } else {
    // V: transpose 64x64 wave tile in LDS ([d][s], stride 72 u16 = 144B, b128-aligned), store Vt[d][s]
    ushort_t* vw = (ushort_t*)(lds + w * 9216);
#pragma unroll
    for (int mf = 0; mf < 4; ++mf)
#pragma unroll
      for (int nf = 0; nf < 4; ++nf)
#pragma unroll
        for (int i = 0; i < 4; ++i) {
          int r = mf * 16 + (l >> 4) * 4 + i;
          int d = nf * 16 + (l & 15);
          float v = acc[mf][nf][i] + bias[nn0 + d];
          vw[d * 72 + r] = f2bf(v);
        }
    // same-wave LDS RAW: compiler orders + waits
#pragma unroll
    for (int it = 0; it < 8; ++it) {
      int dr = it * 8 + (l >> 3);
      int sc = (l & 7) * 8;
      short8 vv = *(const short8*)((const char*)vw + dr * 144 + sc * 2);
      *(short8*)((char*)Vt + (((size_t)(bb * 16 + hh) * 64 + dr) * 2048 + s0 + sc) * 2) = vv;
    }
  }
}

// ---------------- flash attention fwd ----------------
// grid (32, 64): x = q-tile (64 rows), y = b*16+h. 4 waves, 16 q-rows each. KT=64.
__global__ __launch_bounds__(256) void attn_fwd(const ushort_t* __restrict__ Qb,
                                                const ushort_t* __restrict__ Kb,
                                                const ushort_t* __restrict__ Vt,
                                                const float* __restrict__ mask,
                                                float* __restrict__ out) {
  __shared__ char plds[9216];  // per wave: 16 q-rows x 72 u16 (stride 144B, b128-aligned)
  const int tid = threadIdx.x, l = tid & 63, w = tid >> 6;
  const int bh = blockIdx.y;
  const int bb = bh >> 4, hh = bh & 15;
  const int q0 = blockIdx.x * 64 + w * 16;
  char* pw = plds + w * 2304;
  const int lg = l >> 4, lr16 = l & 15;

  const char* qbase = (const char*)Qb + ((size_t)bh * 2048 + q0 + lr16) * 128 + lg * 16;
  short8 aq0 = *(const short8*)(qbase);
  short8 aq1 = *(const short8*)(qbase + 64);

  const float LOG2E = 1.44269504088896340736f;
  const float csc = LOG2E * 0.125f;  // 1/sqrt(64) folded into log2 domain
  float mrun[4], lrun[4];
  f32x4 o[4];
#pragma unroll
  for (int i = 0; i < 4; ++i) { mrun[i] = -1e30f; lrun[i] = 0.f; }
#pragma unroll
  for (int vf = 0; vf < 4; ++vf) o[vf] = (f32x4){0.f, 0.f, 0.f, 0.f};

  const char* kbase = (const char*)Kb + ((size_t)bh * 2048 + lr16) * 128 + lg * 16;
  const char* vbase = (const char*)Vt + ((size_t)bh * 64 + lr16) * 4096 + lg * 16;
  const float* mrow = mask + (size_t)bb * 2048;
  const f32x4 fzero = (f32x4){0.f, 0.f, 0.f, 0.f};

#pragma unroll 1
  for (int kt = 0; kt < 32; ++kt) {
    const char* kb_t = kbase + (size_t)kt * 8192;  // 64 keys * 128B
    f32x4 sfr[4];
#pragma unroll
    for (int kf = 0; kf < 4; ++kf) {
      short8 k0v = *(const short8*)(kb_t + kf * 2048);
      short8 k1v = *(const short8*)(kb_t + kf * 2048 + 64);
      sfr[kf] = MFMA16(aq0, k0v, fzero);
      sfr[kf] = MFMA16(aq1, k1v, sfr[kf]);
    }
    float t[4][4];
    float mv[4];
#pragma unroll
    for (int kf = 0; kf < 4; ++kf) mv[kf] = mrow[kt * 64 + kf * 16 + lr16] * LOG2E;
#pragma unroll
    for (int kf = 0; kf < 4; ++kf)
#pragma unroll
      for (int i = 0; i < 4; ++i) t[kf][i] = sfr[kf][i] * csc + mv[kf];

    float alpha[4];
#pragma unroll
    for (int i = 0; i < 4; ++i) {
      float mx = fmaxf(fmaxf(t[0][i], t[1][i]), fmaxf(t[2][i], t[3][i]));
#pragma unroll
      for (int d = 1; d < 16; d <<= 1) mx = fmaxf(mx, __shfl_xor(mx, d));
      float mnew = fmaxf(mrun[i], mx);
      alpha[i] = __builtin_amdgcn_exp2f(mrun[i] - mnew);
      float sum = 0.f;
#pragma unroll
      for (int kf = 0; kf < 4; ++kf) {
        float p = __builtin_amdgcn_exp2f(t[kf][i] - mnew);
        t[kf][i] = p;
        sum += p;
      }
#pragma unroll
      for (int d = 1; d < 16; d <<= 1) sum += __shfl_xor(sum, d);
      lrun[i] = lrun[i] * alpha[i] + sum;
      mrun[i] = mnew;
    }
#pragma unroll
    for (int vf = 0; vf < 4; ++vf)
#pragma unroll
      for (int i = 0; i < 4; ++i) o[vf][i] *= alpha[i];

    // P (D-layout) -> LDS -> A-frag layout
    ushort_t* pu = (ushort_t*)pw;
#pragma unroll
    for (int kf = 0; kf < 4; ++kf)
#pragma unroll
      for (int i = 0; i < 4; ++i)
        pu[(lg * 4 + i) * 72 + kf * 16 + lr16] = f2bf(t[kf][i]);
    short8 pa0 = *(const short8*)(pw + lr16 * 144 + lg * 16);
    short8 pa1 = *(const short8*)(pw + lr16 * 144 + 64 + lg * 16);

    const char* vb_t = vbase + kt * 128;
#pragma unroll
    for (int vf = 0; vf < 4; ++vf) {
      short8 v0 = *(const short8*)(vb_t + (size_t)vf * 16 * 4096);
      short8 v1 = *(const short8*)(vb_t + (size_t)vf * 16 * 4096 + 64);
      o[vf] = MFMA16(pa0, v0, o[vf]);
      o[vf] = MFMA16(pa1, v1, o[vf]);
    }
  }

  float inv[4];
#pragma unroll
  for (int i = 0; i < 4; ++i) inv[i] = 1.0f / lrun[i];
#pragma unroll
  for (int vf = 0; vf < 4; ++vf)
#pragma unroll
    for (int i = 0; i < 4; ++i)
      out[((size_t)bb * 2048 + q0 + lg * 4 + i) * 1024 + hh * 64 + vf * 16 + lr16] =
          o[vf][i] * inv[i];
}

extern "C" void kernel_launch(void* const* d_in, const int* in_sizes, int n_in,
                              void* d_out, int out_size, void* d_ws, size_t ws_size,
                              hipStream_t stream) {
  const float* hs  = (const float*)d_in[0];
  const float* msk = (const float*)d_in[1];
  const float* Wq  = (const float*)d_in[2];
  const float* bq  = (const float*)d_in[3];
  const float* Wk  = (const float*)d_in[4];
  const float* bk  = (const float*)d_in[5];
  const float* Wv  = (const float*)d_in[6];
  const float* bv  = (const float*)d_in[7];
  float* out = (float*)d_out;
  char* ws = (char*)d_ws;
  ushort_t* Xb = (ushort_t*)ws;
  ushort_t* Wt = (ushort_t*)(ws + (16u << 20));
  ushort_t* Qb = (ushort_t*)(ws + (22u << 20));
  ushort_t* Kb = (ushort_t*)(ws + (38u << 20));
  ushort_t* Vt = (ushort_t*)(ws + (54u << 20));

  convert_x<<<4096, 256, 0, stream>>>(hs, Xb);
  convert_w<<<dim3(16, 16, 3), 256, 0, stream>>>(Wq, Wk, Wv, Wt);
  gemm_qkv<<<dim3(64, 24), 256, 0, stream>>>(Xb, Wt, bq, bk, bv, Qb, Kb, Vt);
  attn_fwd<<<dim3(32, 64), 256, 0, stream>>>(Qb, Kb, Vt, msk, out);
}

// Round 3
// 293.662 us; speedup vs baseline: 2.0863x; 2.0863x over previous
//
#include <hip/hip_runtime.h>
#include <hip/hip_bf16.h>
#include <stdint.h>

// BERT self-attention fwd: B=4,S=2048,H=1024,NH=16,HD=64. fp32 in/out, bf16 MFMA compute.
// ws layout: Xb bf16[8192][1024] @0 (16MB) | Wt bf16[3072][1024] @16MB (6MB)
//            Qb bf16[64][2048][64] @22MB (Q pre-scaled by log2e/8) | Kb @38MB | Vt bf16[64][64][2048] @54MB

typedef unsigned short ushort_t;
typedef __attribute__((ext_vector_type(4))) float f32x4;
typedef __attribute__((ext_vector_type(8))) short short8;
typedef __attribute__((ext_vector_type(2))) unsigned int uint2v;

#define MFMA16(a, b, c) __builtin_amdgcn_mfma_f32_16x16x32_bf16((a), (b), (c), 0, 0, 0)

__device__ __forceinline__ ushort_t f2bf(float f) {
  unsigned u = __float_as_uint(f);
  u = (u + 0x7FFFu + ((u >> 16) & 1u)) >> 16;
  return (ushort_t)u;
}

typedef __attribute__((address_space(1))) unsigned int as1_uint;
typedef __attribute__((address_space(3))) unsigned int as3_uint;

// async global->LDS, 16B per lane; lds_dst wave-uniform base (lane writes base + lane*16)
__device__ __forceinline__ void async16(void* lds_dst, const void* g_src) {
  __builtin_amdgcn_global_load_lds((as1_uint*)(uintptr_t)g_src,
                                   (as3_uint*)(unsigned)(uintptr_t)lds_dst, 16, 0, 0);
}

// ---------------- convert X fp32 -> bf16 ----------------
__global__ __launch_bounds__(256) void convert_x(const float* __restrict__ X,
                                                 ushort_t* __restrict__ Xb) {
  int idx = (blockIdx.x * 256 + threadIdx.x) * 8;
  f32x4 a = *(const f32x4*)(X + idx);
  f32x4 b = *(const f32x4*)(X + idx + 4);
  short8 r;
#pragma unroll
  for (int j = 0; j < 4; ++j) r[j] = (short)f2bf(a[j]);
#pragma unroll
  for (int j = 0; j < 4; ++j) r[4 + j] = (short)f2bf(b[j]);
  *(short8*)(Xb + idx) = r;
}

// ---------------- convert + transpose W -> Wt[n][k] bf16, 3 mats stacked ----------------
__global__ __launch_bounds__(256) void convert_w(const float* __restrict__ Wq,
                                                 const float* __restrict__ Wk,
                                                 const float* __restrict__ Wv,
                                                 ushort_t* __restrict__ Wt) {
  const int mat = blockIdx.z;
  const float* W = (mat == 0) ? Wq : ((mat == 1) ? Wk : Wv);
  const int k0 = blockIdx.x * 64, n0 = blockIdx.y * 64;
  __shared__ float t[64][65];
  const int tid = threadIdx.x;
#pragma unroll
  for (int it = 0; it < 16; ++it) {
    int idx = it * 256 + tid;
    int r = idx >> 6, c = idx & 63;
    t[r][c] = W[(size_t)(k0 + r) * 1024 + n0 + c];
  }
  __syncthreads();
#pragma unroll
  for (int it = 0; it < 16; ++it) {
    int idx = it * 256 + tid;
    int nr = idx >> 6, kc = idx & 63;
    Wt[(size_t)(mat * 1024 + n0 + nr) * 1024 + k0 + kc] = f2bf(t[kc][nr]);
  }
}

// ---------------- fused QKV GEMM: C[8192][3072] = Xb @ W, epilogue scatters to Q/K/Vt ----------------
__global__ __launch_bounds__(256) void gemm_qkv(const ushort_t* __restrict__ Xb,
                                                const ushort_t* __restrict__ Wt,
                                                const float* __restrict__ bq,
                                                const float* __restrict__ bk,
                                                const float* __restrict__ bv,
                                                ushort_t* __restrict__ Qb,
                                                ushort_t* __restrict__ Kb,
                                                ushort_t* __restrict__ Vt) {
  __shared__ char lds[36864];  // A 16KB @0, B 16KB @16384; epilogue V-transpose 4*9216
  const int tid = threadIdx.x;
  const int l = tid & 63, w = tid >> 6;
  const int m0 = blockIdx.x * 128;
  const int n0 = blockIdx.y * 128;
  const int wm = w >> 1, wn = w & 1;

  const int lr = l >> 3;
  const int kb_log = (((l & 7) ^ lr) << 4);
  const char* srcA = (const char*)Xb + (size_t)(m0 + w * 32 + lr) * 2048 + kb_log;
  const char* srcB = (const char*)Wt + (size_t)(n0 + w * 32 + lr) * 2048 + kb_log;
  char* ldsA_w = lds + w * 4096;
  char* ldsB_w = lds + 16384 + w * 4096;

  const int ra = wm * 64 + (l & 15);
  const int rb = wn * 64 + (l & 15);
  const int swz = (l & 7) << 4;
  const int x0 = (((l >> 4) << 4)) ^ swz;
  const int x1 = (64 + ((l >> 4) << 4)) ^ swz;

  f32x4 acc[4][4];
#pragma unroll
  for (int mf = 0; mf < 4; ++mf)
#pragma unroll
    for (int nf = 0; nf < 4; ++nf) acc[mf][nf] = (f32x4){0.f, 0.f, 0.f, 0.f};

#pragma unroll 1
  for (int kt = 0; kt < 16; ++kt) {
    if (kt) __syncthreads();
    const int koff = kt * 128;
#pragma unroll
    for (int c = 0; c < 4; ++c) {
      async16(ldsA_w + c * 1024, srcA + c * 16384 + koff);
      async16(ldsB_w + c * 1024, srcB + c * 16384 + koff);
    }
    __syncthreads();
#pragma unroll
    for (int half = 0; half < 2; ++half) {
      const int xo = half ? x1 : x0;
      short8 av[4], bv2[4];
#pragma unroll
      for (int mf = 0; mf < 4; ++mf)
        av[mf] = *(const short8*)(lds + (ra + mf * 16) * 128 + xo);
#pragma unroll
      for (int nf = 0; nf < 4; ++nf)
        bv2[nf] = *(const short8*)(lds + 16384 + (rb + nf * 16) * 128 + xo);
#pragma unroll
      for (int mf = 0; mf < 4; ++mf)
#pragma unroll
        for (int nf = 0; nf < 4; ++nf)
          acc[mf][nf] = MFMA16(av[mf], bv2[nf], acc[mf][nf]);
    }
  }

  __syncthreads();
  // epilogue
  const int col0 = n0 + wn * 64;
  const int mat = col0 >> 10;
  const int nn0 = col0 & 1023;
  const int hh = nn0 >> 6;
  const int row0 = m0 + wm * 64;
  const int bb = row0 >> 11;
  const int s0 = row0 & 2047;
  const float* bias = (mat == 0) ? bq : ((mat == 1) ? bk : bv);
  const float qscale = 0.18033688011112042f;  // log2(e)/sqrt(64), folded into Q
  if (mat < 2) {
    ushort_t* dst = (mat == 0) ? Qb : Kb;
    const float scl = (mat == 0) ? qscale : 1.0f;
#pragma unroll
    for (int mf = 0; mf < 4; ++mf)
#pragma unroll
      for (int nf = 0; nf < 4; ++nf)
#pragma unroll
        for (int i = 0; i < 4; ++i) {
          int r = mf * 16 + (l >> 4) * 4 + i;
          int d = nf * 16 + (l & 15);
          float v = (acc[mf][nf][i] + bias[nn0 + d]) * scl;
          dst[((size_t)(bb * 16 + hh) * 2048 + (s0 + r)) * 64 + d] = f2bf(v);
        }
  } else {
    ushort_t* vw = (ushort_t*)(lds + w * 9216);
#pragma unroll
    for (int mf = 0; mf < 4; ++mf)
#pragma unroll
      for (int nf = 0; nf < 4; ++nf)
#pragma unroll
        for (int i = 0; i < 4; ++i) {
          int r = mf * 16 + (l >> 4) * 4 + i;
          int d = nf * 16 + (l & 15);
          float v = acc[mf][nf][i] + bias[nn0 + d];
          vw[d * 72 + r] = f2bf(v);
        }
#pragma unroll
    for (int it = 0; it < 8; ++it) {
      int dr = it * 8 + (l >> 3);
      int sc = (l & 7) * 8;
      short8 vv = *(const short8*)((const char*)vw + dr * 144 + sc * 2);
      *(short8*)((char*)Vt + (((size_t)(bb * 16 + hh) * 64 + dr) * 2048 + s0 + sc) * 2) = vv;
    }
  }
}

// ---------------- flash attention fwd, swapped-QK^T lane-local softmax ----------------
// grid (32, 64): x = q-tile (64 rows), y = b*16+h. 4 waves x 16 q-rows. KVBLK=64.
// LDS: klds 8KB @0 | vlds 8KB @8192 | plds 4x2KB @16384 | albuf 4x64B @24576
__global__ __launch_bounds__(256) void attn_fwd(const ushort_t* __restrict__ Qb,
                                                const ushort_t* __restrict__ Kb,
                                                const ushort_t* __restrict__ Vt,
                                                const float* __restrict__ mask,
                                                float* __restrict__ out) {
  __shared__ char lds[24832];
  const int tid = threadIdx.x, l = tid & 63, w = tid >> 6;
  const int bh = blockIdx.y;
  const int bb = bh >> 4, hh = bh & 15;
  const int q0 = blockIdx.x * 64;
  const int lg = l >> 4, lr = l & 15;
  char* klds = lds;
  char* vlds = lds + 8192;
  char* pl = lds + 16384 + w * 2048;
  float* albuf = (float*)(lds + 24576 + w * 64);

  const float LOG2E = 1.44269504088896340736f;
  const f32x4 fzero = (f32x4){0.f, 0.f, 0.f, 0.f};
  const int psz = (lr & 7) << 4;  // XOR swizzle for row (.. & 7) == lr & 7

  // Q (pre-scaled) into regs: B-frag, col=q=lr, k packed 8/lane
  const char* qbase = (const char*)Qb + ((size_t)bh * 2048 + q0 + w * 16 + lr) * 128 + lg * 16;
  short8 aq0 = *(const short8*)(qbase);
  short8 aq1 = *(const short8*)(qbase + 64);

  // staging sources (inverse-swizzled global col so linear LDS dest + swizzled reads agree)
  const int srow = l >> 3;
  const int scol = ((l & 7) ^ srow) << 4;
  const char* ksrc0 = (const char*)Kb + (size_t)bh * 2048 * 128 + (size_t)(w * 16 + srow) * 128 + scol;
  const char* vsrc0 = (const char*)Vt + ((size_t)bh * 64 + w * 16 + srow) * 4096 + scol;
  char* kdst = klds + w * 2048;
  char* vdst = vlds + w * 2048;

  const float* mrow = mask + (size_t)bb * 2048;

  float mrun = -1e30f, lrun = 0.f;  // per q=lr, replicated across lg
  f32x4 o[4];
#pragma unroll
  for (int vf = 0; vf < 4; ++vf) o[vf] = fzero;

#pragma unroll 1
  for (int kt = 0; kt < 32; ++kt) {
    __syncthreads();  // prev tile consumed by all waves
    const int kb_off = kt * 8192;  // 64 key-rows * 128B
    async16(kdst, ksrc0 + kb_off);
    async16(kdst + 1024, ksrc0 + kb_off + 1024);
    async16(vdst, vsrc0 + kt * 128);
    async16(vdst + 1024, vsrc0 + 8 * 4096 + kt * 128);
    f32x4 mkv[4];
#pragma unroll
    for (int kf = 0; kf < 4; ++kf)
      mkv[kf] = *(const f32x4*)(mrow + kt * 64 + kf * 16 + lg * 4);
    asm volatile("s_waitcnt vmcnt(0)" ::: "memory");
    __syncthreads();  // tile visible

    // QK^T swapped: A = K rows, B = Q. D[key][q]: q=lr, key=kf*16+lg*4+i. Already log2-scaled.
    float t4[4][4];
#pragma unroll
    for (int kf = 0; kf < 4; ++kf) {
      const char* ka = klds + (kf * 16 + lr) * 128;
      short8 a0 = *(const short8*)(ka + ((lg * 16) ^ psz));
      short8 a1 = *(const short8*)(ka + ((64 + lg * 16) ^ psz));
      f32x4 s = MFMA16(a0, aq0, fzero);
      s = MFMA16(a1, aq1, s);
#pragma unroll
      for (int i = 0; i < 4; ++i) t4[kf][i] = fmaf(mkv[kf][i], LOG2E, s[i]);
    }

    // lane-local max over 16 keys + 2 cross-lane reduces
    float mx0 = fmaxf(fmaxf(t4[0][0], t4[0][1]), fmaxf(t4[0][2], t4[0][3]));
    float mx1 = fmaxf(fmaxf(t4[1][0], t4[1][1]), fmaxf(t4[1][2], t4[1][3]));
    float mx2 = fmaxf(fmaxf(t4[2][0], t4[2][1]), fmaxf(t4[2][2], t4[2][3]));
    float mx3 = fmaxf(fmaxf(t4[3][0], t4[3][1]), fmaxf(t4[3][2], t4[3][3]));
    float mx = fmaxf(fmaxf(mx0, mx1), fmaxf(mx2, mx3));
    mx = fmaxf(mx, __shfl_xor(mx, 16));
    mx = fmaxf(mx, __shfl_xor(mx, 32));
    float mnew = fmaxf(mrun, mx);
    float alpha = __builtin_amdgcn_exp2f(mrun - mnew);
    mrun = mnew;

    float p[4][4];
    float sum = 0.f;
#pragma unroll
    for (int kf = 0; kf < 4; ++kf) {
      f32x4 ps;
#pragma unroll
      for (int i = 0; i < 4; ++i) {
        ps[i] = __builtin_amdgcn_exp2f(t4[kf][i] - mnew);
        p[kf][i] = ps[i];
      }
      sum += (ps[0] + ps[1]) + (ps[2] + ps[3]);
    }
    sum += __shfl_xor(sum, 16);
    sum += __shfl_xor(sum, 32);
    lrun = lrun * alpha + sum;

    // pack P -> bf16 pairs, 4x ds_write_b64 into swizzled pl[q][key]
#pragma unroll
    for (int kf = 0; kf < 4; ++kf) {
      unsigned w0, w1;
      asm("v_cvt_pk_bf16_f32 %0, %1, %2" : "=v"(w0) : "v"(p[kf][0]), "v"(p[kf][1]));
      asm("v_cvt_pk_bf16_f32 %0, %1, %2" : "=v"(w1) : "v"(p[kf][2]), "v"(p[kf][3]));
      uint2v pw2 = {w0, w1};
      *(uint2v*)(pl + lr * 128 + ((kf * 32 + lg * 8) ^ psz)) = pw2;
    }

    // alpha broadcast softmax-layout (q=lr) -> O-layout (q=lg*4+i)
    if (lg == 0) albuf[lr] = alpha;
    f32x4 al4 = *(const f32x4*)(albuf + lg * 4);
#pragma unroll
    for (int vf = 0; vf < 4; ++vf)
#pragma unroll
      for (int i = 0; i < 4; ++i) o[vf][i] *= al4[i];

    // PV: A = P[q][key], B = V^T[d][key]
    short8 pa0 = *(const short8*)(pl + lr * 128 + ((lg * 16) ^ psz));
    short8 pa1 = *(const short8*)(pl + lr * 128 + ((64 + lg * 16) ^ psz));
#pragma unroll
    for (int vf = 0; vf < 4; ++vf) {
      const char* vb = vlds + (vf * 16 + lr) * 128;
      short8 v0 = *(const short8*)(vb + ((lg * 16) ^ psz));
      short8 v1 = *(const short8*)(vb + ((64 + lg * 16) ^ psz));
      o[vf] = MFMA16(pa0, v0, o[vf]);
      o[vf] = MFMA16(pa1, v1, o[vf]);
    }
  }

  // final 1/l broadcast, write out
  if (lg == 0) albuf[lr] = lrun;
  f32x4 l4 = *(const f32x4*)(albuf + lg * 4);
  f32x4 inv4;
#pragma unroll
  for (int i = 0; i < 4; ++i) inv4[i] = 1.0f / l4[i];
#pragma unroll
  for (int vf = 0; vf < 4; ++vf)
#pragma unroll
    for (int i = 0; i < 4; ++i)
      out[((size_t)bb * 2048 + q0 + w * 16 + lg * 4 + i) * 1024 + hh * 64 + vf * 16 + lr] =
          o[vf][i] * inv4[i];
}

extern "C" void kernel_launch(void* const* d_in, const int* in_sizes, int n_in,
                              void* d_out, int out_size, void* d_ws, size_t ws_size,
                              hipStream_t stream) {
  const float* hs  = (const float*)d_in[0];
  const float* msk = (const float*)d_in[1];
  const float* Wq  = (const float*)d_in[2];
  const float* bq  = (const float*)d_in[3];
  const float* Wk  = (const float*)d_in[4];
  const float* bk  = (const float*)d_in[5];
  const float* Wv  = (const float*)d_in[6];
  const float* bv  = (const float*)d_in[7];
  float* out = (float*)d_out;
  char* ws = (char*)d_ws;
  ushort_t* Xb = (ushort_t*)ws;
  ushort_t* Wt = (ushort_t*)(ws + (16u << 20));
  ushort_t* Qb = (ushort_t*)(ws + (22u << 20));
  ushort_t* Kb = (ushort_t*)(ws + (38u << 20));
  ushort_t* Vt = (ushort_t*)(ws + (54u << 20));

  convert_x<<<4096, 256, 0, stream>>>(hs, Xb);
  convert_w<<<dim3(16, 16, 3), 256, 0, stream>>>(Wq, Wk, Wv, Wt);
  gemm_qkv<<<dim3(64, 24), 256, 0, stream>>>(Xb, Wt, bq, bk, bv, Qb, Kb, Vt);
  attn_fwd<<<dim3(32, 64), 256, 0, stream>>>(Qb, Kb, Vt, msk, out);
}

// Round 4
// 279.318 us; speedup vs baseline: 2.1935x; 1.0514x over previous
//
#include <hip/hip_runtime.h>
#include <hip/hip_bf16.h>
#include <stdint.h>

// BERT self-attention fwd: B=4,S=2048,H=1024,NH=16,HD=64. fp32 in/out, bf16 MFMA compute.
// ws layout: Xb bf16[8192][1024] @0 (16MB) | Wt bf16[3072][1024] @16MB (6MB)
//            Qb bf16[64][2048][64] @22MB (Q pre-scaled by log2e/8) | Kb @38MB | Vt bf16[64][64][2048] @54MB

typedef unsigned short ushort_t;
typedef __attribute__((ext_vector_type(4))) float f32x4;
typedef __attribute__((ext_vector_type(8))) short short8;
typedef __attribute__((ext_vector_type(2))) unsigned int uint2v;

#define MFMA16(a, b, c) __builtin_amdgcn_mfma_f32_16x16x32_bf16((a), (b), (c), 0, 0, 0)

__device__ __forceinline__ ushort_t f2bf(float f) {
  unsigned u = __float_as_uint(f);
  u = (u + 0x7FFFu + ((u >> 16) & 1u)) >> 16;
  return (ushort_t)u;
}

typedef __attribute__((address_space(1))) unsigned int as1_uint;
typedef __attribute__((address_space(3))) unsigned int as3_uint;

// async global->LDS, 16B per lane; lds_dst wave-uniform base (lane writes base + lane*16)
__device__ __forceinline__ void async16(void* lds_dst, const void* g_src) {
  __builtin_amdgcn_global_load_lds((as1_uint*)(uintptr_t)g_src,
                                   (as3_uint*)(unsigned)(uintptr_t)lds_dst, 16, 0, 0);
}

// ---------------- convert X fp32 -> bf16 ----------------
__global__ __launch_bounds__(256) void convert_x(const float* __restrict__ X,
                                                 ushort_t* __restrict__ Xb) {
  int idx = (blockIdx.x * 256 + threadIdx.x) * 8;
  f32x4 a = *(const f32x4*)(X + idx);
  f32x4 b = *(const f32x4*)(X + idx + 4);
  short8 r;
#pragma unroll
  for (int j = 0; j < 4; ++j) r[j] = (short)f2bf(a[j]);
#pragma unroll
  for (int j = 0; j < 4; ++j) r[4 + j] = (short)f2bf(b[j]);
  *(short8*)(Xb + idx) = r;
}

// ---------------- convert + transpose W -> Wt[n][k] bf16, 3 mats stacked ----------------
__global__ __launch_bounds__(256) void convert_w(const float* __restrict__ Wq,
                                                 const float* __restrict__ Wk,
                                                 const float* __restrict__ Wv,
                                                 ushort_t* __restrict__ Wt) {
  const int mat = blockIdx.z;
  const float* W = (mat == 0) ? Wq : ((mat == 1) ? Wk : Wv);
  const int k0 = blockIdx.x * 64, n0 = blockIdx.y * 64;
  __shared__ float t[64][65];
  const int tid = threadIdx.x;
#pragma unroll
  for (int it = 0; it < 16; ++it) {
    int idx = it * 256 + tid;
    int r = idx >> 6, c = idx & 63;
    t[r][c] = W[(size_t)(k0 + r) * 1024 + n0 + c];
  }
  __syncthreads();
#pragma unroll
  for (int it = 0; it < 16; ++it) {
    int idx = it * 256 + tid;
    int nr = idx >> 6, kc = idx & 63;
    Wt[(size_t)(mat * 1024 + n0 + nr) * 1024 + k0 + kc] = f2bf(t[kc][nr]);
  }
}

// ---------------- fused QKV GEMM: C[8192][3072] = Xb @ W, epilogue scatters to Q/K/Vt ----------------
__global__ __launch_bounds__(256) void gemm_qkv(const ushort_t* __restrict__ Xb,
                                                const ushort_t* __restrict__ Wt,
                                                const float* __restrict__ bq,
                                                const float* __restrict__ bk,
                                                const float* __restrict__ bv,
                                                ushort_t* __restrict__ Qb,
                                                ushort_t* __restrict__ Kb,
                                                ushort_t* __restrict__ Vt) {
  __shared__ char lds[36864];  // A 16KB @0, B 16KB @16384; epilogue V-transpose 4*9216
  const int tid = threadIdx.x;
  const int l = tid & 63, w = tid >> 6;
  const int m0 = blockIdx.x * 128;
  const int n0 = blockIdx.y * 128;
  const int wm = w >> 1, wn = w & 1;

  const int lr = l >> 3;
  const int kb_log = (((l & 7) ^ lr) << 4);
  const char* srcA = (const char*)Xb + (size_t)(m0 + w * 32 + lr) * 2048 + kb_log;
  const char* srcB = (const char*)Wt + (size_t)(n0 + w * 32 + lr) * 2048 + kb_log;
  char* ldsA_w = lds + w * 4096;
  char* ldsB_w = lds + 16384 + w * 4096;

  const int ra = wm * 64 + (l & 15);
  const int rb = wn * 64 + (l & 15);
  const int swz = (l & 7) << 4;
  const int x0 = (((l >> 4) << 4)) ^ swz;
  const int x1 = (64 + ((l >> 4) << 4)) ^ swz;

  f32x4 acc[4][4];
#pragma unroll
  for (int mf = 0; mf < 4; ++mf)
#pragma unroll
    for (int nf = 0; nf < 4; ++nf) acc[mf][nf] = (f32x4){0.f, 0.f, 0.f, 0.f};

#pragma unroll 1
  for (int kt = 0; kt < 16; ++kt) {
    if (kt) __syncthreads();
    const int koff = kt * 128;
#pragma unroll
    for (int c = 0; c < 4; ++c) {
      async16(ldsA_w + c * 1024, srcA + c * 16384 + koff);
      async16(ldsB_w + c * 1024, srcB + c * 16384 + koff);
    }
    __syncthreads();
#pragma unroll
    for (int half = 0; half < 2; ++half) {
      const int xo = half ? x1 : x0;
      short8 av[4], bv2[4];
#pragma unroll
      for (int mf = 0; mf < 4; ++mf)
        av[mf] = *(const short8*)(lds + (ra + mf * 16) * 128 + xo);
#pragma unroll
      for (int nf = 0; nf < 4; ++nf)
        bv2[nf] = *(const short8*)(lds + 16384 + (rb + nf * 16) * 128 + xo);
#pragma unroll
      for (int mf = 0; mf < 4; ++mf)
#pragma unroll
        for (int nf = 0; nf < 4; ++nf)
          acc[mf][nf] = MFMA16(av[mf], bv2[nf], acc[mf][nf]);
    }
  }

  __syncthreads();
  // epilogue
  const int col0 = n0 + wn * 64;
  const int mat = col0 >> 10;
  const int nn0 = col0 & 1023;
  const int hh = nn0 >> 6;
  const int row0 = m0 + wm * 64;
  const int bb = row0 >> 11;
  const int s0 = row0 & 2047;
  const float* bias = (mat == 0) ? bq : ((mat == 1) ? bk : bv);
  const float qscale = 0.18033688011112042f;  // log2(e)/sqrt(64), folded into Q
  if (mat < 2) {
    ushort_t* dst = (mat == 0) ? Qb : Kb;
    const float scl = (mat == 0) ? qscale : 1.0f;
#pragma unroll
    for (int mf = 0; mf < 4; ++mf)
#pragma unroll
      for (int nf = 0; nf < 4; ++nf)
#pragma unroll
        for (int i = 0; i < 4; ++i) {
          int r = mf * 16 + (l >> 4) * 4 + i;
          int d = nf * 16 + (l & 15);
          float v = (acc[mf][nf][i] + bias[nn0 + d]) * scl;
          dst[((size_t)(bb * 16 + hh) * 2048 + (s0 + r)) * 64 + d] = f2bf(v);
        }
  } else {
    ushort_t* vw = (ushort_t*)(lds + w * 9216);
#pragma unroll
    for (int mf = 0; mf < 4; ++mf)
#pragma unroll
      for (int nf = 0; nf < 4; ++nf)
#pragma unroll
        for (int i = 0; i < 4; ++i) {
          int r = mf * 16 + (l >> 4) * 4 + i;
          int d = nf * 16 + (l & 15);
          float v = acc[mf][nf][i] + bias[nn0 + d];
          vw[d * 72 + r] = f2bf(v);
        }
#pragma unroll
    for (int it = 0; it < 8; ++it) {
      int dr = it * 8 + (l >> 3);
      int sc = (l & 7) * 8;
      short8 vv = *(const short8*)((const char*)vw + dr * 144 + sc * 2);
      *(short8*)((char*)Vt + (((size_t)(bb * 16 + hh) * 64 + dr) * 2048 + s0 + sc) * 2) = vv;
    }
  }
}

// ---------------- flash attention fwd: swapped QK^T, static-max softmax, dbuf K/V ----------------
// grid (32, 64): x = q-tile (64 rows), y = b*16+h. 4 waves x 16 q-rows. KVBLK=64.
// LDS: klds 2x8KB @0 | vlds 2x8KB @16384 | plds 4x2KB @32768 | mlds f32[2048] @40960 | sbuf @49152
__global__ __launch_bounds__(256) void attn_fwd(const ushort_t* __restrict__ Qb,
                                                const ushort_t* __restrict__ Kb,
                                                const ushort_t* __restrict__ Vt,
                                                const float* __restrict__ mask,
                                                float* __restrict__ out) {
  __shared__ char lds[49408];
  const int tid = threadIdx.x, l = tid & 63, w = tid >> 6;
  const int bh = blockIdx.y;
  const int bb = bh >> 4, hh = bh & 15;
  const int q0 = blockIdx.x * 64;
  const int lg = l >> 4, lr = l & 15;
  char* klds = lds;
  char* vlds = lds + 16384;
  char* pl = lds + 32768 + w * 2048;
  float* ml = (float*)(lds + 40960);
  float* sbuf = (float*)(lds + 49152 + w * 64);

  const float LOG2E = 1.44269504088896340736f;
  const f32x4 fzero = (f32x4){0.f, 0.f, 0.f, 0.f};
  const int psz = (lr & 7) << 4;  // XOR swizzle; row&7 == lr&7 for all swizzled rows

  // Q (pre-scaled by log2e/8) into regs: B-frag, col=q=lr, k packed 8/lane
  const char* qbase = (const char*)Qb + ((size_t)bh * 2048 + q0 + w * 16 + lr) * 128 + lg * 16;
  short8 aq0 = *(const short8*)(qbase);
  short8 aq1 = *(const short8*)(qbase + 64);

  // staging sources (inverse-swizzled global col so linear LDS dest + swizzled reads agree)
  const int srow = l >> 3;
  const int scol = ((l & 7) ^ srow) << 4;
  const char* ksrc0 = (const char*)Kb + (size_t)bh * 2048 * 128 + (size_t)(w * 16 + srow) * 128 + scol;
  const char* vsrc0 = (const char*)Vt + ((size_t)bh * 64 + w * 16 + srow) * 4096 + scol;

  // prologue: stage tile 0 into buf 0
  {
    char* kd = klds + w * 2048;
    char* vd = vlds + w * 2048;
    async16(kd, ksrc0);
    async16(kd + 1024, ksrc0 + 1024);
    async16(vd, vsrc0);
    async16(vd + 1024, vsrc0 + 8 * 4096);
  }
  // mask row -> LDS, folded by log2e (read once per block)
  {
    const float* mrow = mask + (size_t)bb * 2048;
    int mi = tid * 8;
    f32x4 a = *(const f32x4*)(mrow + mi);
    f32x4 b = *(const f32x4*)(mrow + mi + 4);
#pragma unroll
    for (int j = 0; j < 4; ++j) { a[j] *= LOG2E; b[j] *= LOG2E; }
    *(f32x4*)(ml + mi) = a;
    *(f32x4*)(ml + mi + 4) = b;
  }

  f32x4 lsum = fzero;  // per q=lr partial sums (lane-local; reduced after loop)
  f32x4 o[4];
#pragma unroll
  for (int vf = 0; vf < 4; ++vf) o[vf] = fzero;

#pragma unroll 1
  for (int kt = 0; kt < 32; ++kt) {
    const int cur = kt & 1;
    // barrier 1: everyone done reading buf[cur^1] -> safe to overwrite
    asm volatile("s_waitcnt lgkmcnt(0)" ::: "memory");
    __builtin_amdgcn_s_barrier();
    if (kt < 31) {
      char* kd = klds + (cur ^ 1) * 8192 + w * 2048;
      char* vd = vlds + (cur ^ 1) * 8192 + w * 2048;
      const char* ks = ksrc0 + (size_t)(kt + 1) * 8192;
      const char* vs = vsrc0 + (kt + 1) * 128;
      async16(kd, ks);
      async16(kd + 1024, ks + 1024);
      async16(vd, vs);
      async16(vd + 1024, vs + 8 * 4096);
      asm volatile("s_waitcnt vmcnt(4)" ::: "memory");  // tile kt done; kt+1 in flight
    } else {
      asm volatile("s_waitcnt vmcnt(0)" ::: "memory");
    }
    __builtin_amdgcn_s_barrier();  // buf[cur] visible to all waves
    __builtin_amdgcn_sched_barrier(0);

    const char* kb = klds + cur * 8192;
    const char* vb = vlds + cur * 8192;

    // QK^T swapped: A = K rows, B = Q. D[key][q]: q=lr, key=kf*16+lg*4+i. log2 domain.
#pragma unroll
    for (int kf = 0; kf < 4; ++kf) {
      const char* ka = kb + (kf * 16 + lr) * 128;
      short8 a0 = *(const short8*)(ka + ((lg * 16) ^ psz));
      short8 a1 = *(const short8*)(ka + ((64 + lg * 16) ^ psz));
      f32x4 s = MFMA16(a0, aq0, fzero);
      s = MFMA16(a1, aq1, s);
      f32x4 m4 = *(const f32x4*)(ml + kt * 64 + kf * 16 + lg * 4);
      f32x4 ps;
#pragma unroll
      for (int i = 0; i < 4; ++i) ps[i] = __builtin_amdgcn_exp2f(s[i] + m4[i]);
      lsum += ps;
      unsigned w0, w1;
      asm("v_cvt_pk_bf16_f32 %0, %1, %2" : "=v"(w0) : "v"(ps[0]), "v"(ps[1]));
      asm("v_cvt_pk_bf16_f32 %0, %1, %2" : "=v"(w1) : "v"(ps[2]), "v"(ps[3]));
      uint2v pw2 = {w0, w1};
      *(uint2v*)(pl + lr * 128 + ((kf * 32 + lg * 8) ^ psz)) = pw2;
    }

    // PV: A = P[q][key], B = V^T[d][key]  (same-wave LDS RAW; compiler waits)
    short8 pa0 = *(const short8*)(pl + lr * 128 + ((lg * 16) ^ psz));
    short8 pa1 = *(const short8*)(pl + lr * 128 + ((64 + lg * 16) ^ psz));
#pragma unroll
    for (int vf = 0; vf < 4; ++vf) {
      const char* vrow = vb + (vf * 16 + lr) * 128;
      short8 v0 = *(const short8*)(vrow + ((lg * 16) ^ psz));
      short8 v1 = *(const short8*)(vrow + ((64 + lg * 16) ^ psz));
      o[vf] = MFMA16(pa0, v0, o[vf]);
      o[vf] = MFMA16(pa1, v1, o[vf]);
    }
  }

  // final sum reduce (deferred): lane-local 4 -> cross-lg -> broadcast to O layout
  float lrun = (lsum[0] + lsum[1]) + (lsum[2] + lsum[3]);
  lrun += __shfl_xor(lrun, 16);
  lrun += __shfl_xor(lrun, 32);
  if (lg == 0) sbuf[lr] = lrun;
  f32x4 l4 = *(const f32x4*)(sbuf + lg * 4);
  f32x4 inv4;
#pragma unroll
  for (int i = 0; i < 4; ++i) inv4[i] = 1.0f / l4[i];
#pragma unroll
  for (int vf = 0; vf < 4; ++vf)
#pragma unroll
    for (int i = 0; i < 4; ++i)
      out[((size_t)bb * 2048 + q0 + w * 16 + lg * 4 + i) * 1024 + hh * 64 + vf * 16 + lr] =
          o[vf][i] * inv4[i];
}

extern "C" void kernel_launch(void* const* d_in, const int* in_sizes, int n_in,
                              void* d_out, int out_size, void* d_ws, size_t ws_size,
                              hipStream_t stream) {
  const float* hs  = (const float*)d_in[0];
  const float* msk = (const float*)d_in[1];
  const float* Wq  = (const float*)d_in[2];
  const float* bq  = (const float*)d_in[3];
  const float* Wk  = (const float*)d_in[4];
  const float* bk  = (const float*)d_in[5];
  const float* Wv  = (const float*)d_in[6];
  const float* bv  = (const float*)d_in[7];
  float* out = (float*)d_out;
  char* ws = (char*)d_ws;
  ushort_t* Xb = (ushort_t*)ws;
  ushort_t* Wt = (ushort_t*)(ws + (16u << 20));
  ushort_t* Qb = (ushort_t*)(ws + (22u << 20));
  ushort_t* Kb = (ushort_t*)(ws + (38u << 20));
  ushort_t* Vt = (ushort_t*)(ws + (54u << 20));

  convert_x<<<4096, 256, 0, stream>>>(hs, Xb);
  convert_w<<<dim3(16, 16, 3), 256, 0, stream>>>(Wq, Wk, Wv, Wt);
  gemm_qkv<<<dim3(64, 24), 256, 0, stream>>>(Xb, Wt, bq, bk, bv, Qb, Kb, Vt);
  attn_fwd<<<dim3(32, 64), 256, 0, stream>>>(Qb, Kb, Vt, msk, out);
}

// Round 5
// 279.045 us; speedup vs baseline: 2.1956x; 1.0010x over previous
//
#include <hip/hip_runtime.h>
#include <hip/hip_bf16.h>
#include <stdint.h>

// BERT self-attention fwd: B=4,S=2048,H=1024,NH=16,HD=64. fp32 in/out, bf16 MFMA compute.
// ws layout: Xb bf16[8192][1024] @0 (16MB) | Wt bf16[3072][1024] @16MB (6MB)
//            Qb bf16[64][2048][64] @22MB (Q pre-scaled by log2e/8) | Kb @38MB | Vt bf16[64][64][2048] @54MB

typedef unsigned short ushort_t;
typedef __attribute__((ext_vector_type(4))) float f32x4;
typedef __attribute__((ext_vector_type(8))) short short8;
typedef __attribute__((ext_vector_type(2))) unsigned int uint2v;

#define MFMA16(a, b, c) __builtin_amdgcn_mfma_f32_16x16x32_bf16((a), (b), (c), 0, 0, 0)

__device__ __forceinline__ ushort_t f2bf(float f) {
  unsigned u = __float_as_uint(f);
  u = (u + 0x7FFFu + ((u >> 16) & 1u)) >> 16;
  return (ushort_t)u;
}

typedef __attribute__((address_space(1))) unsigned int as1_uint;
typedef __attribute__((address_space(3))) unsigned int as3_uint;

// async global->LDS, 16B per lane; lds_dst wave-uniform base (lane writes base + lane*16)
__device__ __forceinline__ void async16(void* lds_dst, const void* g_src) {
  __builtin_amdgcn_global_load_lds((as1_uint*)(uintptr_t)g_src,
                                   (as3_uint*)(unsigned)(uintptr_t)lds_dst, 16, 0, 0);
}

// ---------------- convert X fp32 -> bf16 ----------------
__global__ __launch_bounds__(256) void convert_x(const float* __restrict__ X,
                                                 ushort_t* __restrict__ Xb) {
  int idx = (blockIdx.x * 256 + threadIdx.x) * 8;
  f32x4 a = *(const f32x4*)(X + idx);
  f32x4 b = *(const f32x4*)(X + idx + 4);
  short8 r;
#pragma unroll
  for (int j = 0; j < 4; ++j) r[j] = (short)f2bf(a[j]);
#pragma unroll
  for (int j = 0; j < 4; ++j) r[4 + j] = (short)f2bf(b[j]);
  *(short8*)(Xb + idx) = r;
}

// ---------------- convert + transpose W -> Wt[n][k] bf16, 3 mats stacked ----------------
__global__ __launch_bounds__(256) void convert_w(const float* __restrict__ Wq,
                                                 const float* __restrict__ Wk,
                                                 const float* __restrict__ Wv,
                                                 ushort_t* __restrict__ Wt) {
  const int mat = blockIdx.z;
  const float* W = (mat == 0) ? Wq : ((mat == 1) ? Wk : Wv);
  const int k0 = blockIdx.x * 64, n0 = blockIdx.y * 64;
  __shared__ float t[64][65];
  const int tid = threadIdx.x;
#pragma unroll
  for (int it = 0; it < 16; ++it) {
    int idx = it * 256 + tid;
    int r = idx >> 6, c = idx & 63;
    t[r][c] = W[(size_t)(k0 + r) * 1024 + n0 + c];
  }
  __syncthreads();
#pragma unroll
  for (int it = 0; it < 16; ++it) {
    int idx = it * 256 + tid;
    int nr = idx >> 6, kc = idx & 63;
    Wt[(size_t)(mat * 1024 + n0 + nr) * 1024 + k0 + kc] = f2bf(t[kc][nr]);
  }
}

// ---------------- fused QKV GEMM: C[8192][3072] = Xb @ W, epilogue scatters to Q/K/Vt ----------------
__global__ __launch_bounds__(256) void gemm_qkv(const ushort_t* __restrict__ Xb,
                                                const ushort_t* __restrict__ Wt,
                                                const float* __restrict__ bq,
                                                const float* __restrict__ bk,
                                                const float* __restrict__ bv,
                                                ushort_t* __restrict__ Qb,
                                                ushort_t* __restrict__ Kb,
                                                ushort_t* __restrict__ Vt) {
  __shared__ char lds[36864];  // A 16KB @0, B 16KB @16384; epilogue V-transpose 4*9216
  const int tid = threadIdx.x;
  const int l = tid & 63, w = tid >> 6;
  const int m0 = blockIdx.x * 128;
  const int n0 = blockIdx.y * 128;
  const int wm = w >> 1, wn = w & 1;

  const int lr = l >> 3;
  const int kb_log = (((l & 7) ^ lr) << 4);
  const char* srcA = (const char*)Xb + (size_t)(m0 + w * 32 + lr) * 2048 + kb_log;
  const char* srcB = (const char*)Wt + (size_t)(n0 + w * 32 + lr) * 2048 + kb_log;
  char* ldsA_w = lds + w * 4096;
  char* ldsB_w = lds + 16384 + w * 4096;

  const int ra = wm * 64 + (l & 15);
  const int rb = wn * 64 + (l & 15);
  const int swz = (l & 7) << 4;
  const int x0 = (((l >> 4) << 4)) ^ swz;
  const int x1 = (64 + ((l >> 4) << 4)) ^ swz;

  f32x4 acc[4][4];
#pragma unroll
  for (int mf = 0; mf < 4; ++mf)
#pragma unroll
    for (int nf = 0; nf < 4; ++nf) acc[mf][nf] = (f32x4){0.f, 0.f, 0.f, 0.f};

#pragma unroll 1
  for (int kt = 0; kt < 16; ++kt) {
    if (kt) __syncthreads();
    const int koff = kt * 128;
#pragma unroll
    for (int c = 0; c < 4; ++c) {
      async16(ldsA_w + c * 1024, srcA + c * 16384 + koff);
      async16(ldsB_w + c * 1024, srcB + c * 16384 + koff);
    }
    __syncthreads();
#pragma unroll
    for (int half = 0; half < 2; ++half) {
      const int xo = half ? x1 : x0;
      short8 av[4], bv2[4];
#pragma unroll
      for (int mf = 0; mf < 4; ++mf)
        av[mf] = *(const short8*)(lds + (ra + mf * 16) * 128 + xo);
#pragma unroll
      for (int nf = 0; nf < 4; ++nf)
        bv2[nf] = *(const short8*)(lds + 16384 + (rb + nf * 16) * 128 + xo);
#pragma unroll
      for (int mf = 0; mf < 4; ++mf)
#pragma unroll
        for (int nf = 0; nf < 4; ++nf)
          acc[mf][nf] = MFMA16(av[mf], bv2[nf], acc[mf][nf]);
    }
  }

  __syncthreads();
  // epilogue
  const int col0 = n0 + wn * 64;
  const int mat = col0 >> 10;
  const int nn0 = col0 & 1023;
  const int hh = nn0 >> 6;
  const int row0 = m0 + wm * 64;
  const int bb = row0 >> 11;
  const int s0 = row0 & 2047;
  const float* bias = (mat == 0) ? bq : ((mat == 1) ? bk : bv);
  const float qscale = 0.18033688011112042f;  // log2(e)/sqrt(64), folded into Q
  if (mat < 2) {
    ushort_t* dst = (mat == 0) ? Qb : Kb;
    const float scl = (mat == 0) ? qscale : 1.0f;
#pragma unroll
    for (int mf = 0; mf < 4; ++mf)
#pragma unroll
      for (int nf = 0; nf < 4; ++nf)
#pragma unroll
        for (int i = 0; i < 4; ++i) {
          int r = mf * 16 + (l >> 4) * 4 + i;
          int d = nf * 16 + (l & 15);
          float v = (acc[mf][nf][i] + bias[nn0 + d]) * scl;
          dst[((size_t)(bb * 16 + hh) * 2048 + (s0 + r)) * 64 + d] = f2bf(v);
        }
  } else {
    ushort_t* vw = (ushort_t*)(lds + w * 9216);
#pragma unroll
    for (int mf = 0; mf < 4; ++mf)
#pragma unroll
      for (int nf = 0; nf < 4; ++nf)
#pragma unroll
        for (int i = 0; i < 4; ++i) {
          int r = mf * 16 + (l >> 4) * 4 + i;
          int d = nf * 16 + (l & 15);
          float v = acc[mf][nf][i] + bias[nn0 + d];
          vw[d * 72 + r] = f2bf(v);
        }
#pragma unroll
    for (int it = 0; it < 8; ++it) {
      int dr = it * 8 + (l >> 3);
      int sc = (l & 7) * 8;
      short8 vv = *(const short8*)((const char*)vw + dr * 144 + sc * 2);
      *(short8*)((char*)Vt + (((size_t)(bb * 16 + hh) * 64 + dr) * 2048 + s0 + sc) * 2) = vv;
    }
  }
}

// ---------------- flash attention fwd: swapped QK^T, static-max softmax, dbuf K/V, QBLK=128 ----------------
// grid (16, 64): x = q-tile (128 rows), y = b*16+h. 4 waves x 32 q-rows. KVBLK=64.
// LDS: klds 2x8KB @0 | vlds 2x8KB @16384 | plds 4x4KB @32768 | sbuf 4x128B @49152
__global__ __launch_bounds__(256) void attn_fwd(const ushort_t* __restrict__ Qb,
                                                const ushort_t* __restrict__ Kb,
                                                const ushort_t* __restrict__ Vt,
                                                const float* __restrict__ mask,
                                                float* __restrict__ out) {
  __shared__ char lds[49664];
  const int tid = threadIdx.x, l = tid & 63, w = tid >> 6;
  const int bh = blockIdx.y;
  const int bb = bh >> 4, hh = bh & 15;
  const int q0 = blockIdx.x * 128;
  const int lg = l >> 4, lr = l & 15;
  char* klds = lds;
  char* vlds = lds + 16384;
  char* pl = lds + 32768 + w * 4096;
  float* sbuf = (float*)(lds + 49152 + w * 128);

  const float LOG2E = 1.44269504088896340736f;
  const f32x4 fzero = (f32x4){0.f, 0.f, 0.f, 0.f};
  const int psz = (lr & 7) << 4;  // XOR swizzle; row&7 == lr&7 for all swizzled rows

  // Q (pre-scaled by log2e/8) into regs: B-frag per 16-q group, col=q=lr, k packed 8/lane
  const char* qbase = (const char*)Qb + ((size_t)bh * 2048 + q0 + w * 32 + lr) * 128 + lg * 16;
  short8 aq[2][2];
  aq[0][0] = *(const short8*)(qbase);
  aq[0][1] = *(const short8*)(qbase + 64);
  aq[1][0] = *(const short8*)(qbase + 16 * 128);
  aq[1][1] = *(const short8*)(qbase + 16 * 128 + 64);

  // staging sources (inverse-swizzled global col so linear LDS dest + swizzled reads agree)
  const int srow = l >> 3;
  const int scol = ((l & 7) ^ srow) << 4;
  const char* ksrc0 = (const char*)Kb + (size_t)bh * 2048 * 128 + (size_t)(w * 16 + srow) * 128 + scol;
  const char* vsrc0 = (const char*)Vt + ((size_t)bh * 64 + w * 16 + srow) * 4096 + scol;

  // prologue: stage tile 0 into buf 0
  {
    char* kd = klds + w * 2048;
    char* vd = vlds + w * 2048;
    async16(kd, ksrc0);
    async16(kd + 1024, ksrc0 + 1024);
    async16(vd, vsrc0);
    async16(vd + 1024, vsrc0 + 8 * 4096);
  }

  const float* mrow = mask + (size_t)bb * 2048;

  f32x4 lsum[2];
  lsum[0] = fzero;
  lsum[1] = fzero;
  f32x4 o[2][4];
#pragma unroll
  for (int qc = 0; qc < 2; ++qc)
#pragma unroll
    for (int vf = 0; vf < 4; ++vf) o[qc][vf] = fzero;

#pragma unroll 1
  for (int kt = 0; kt < 32; ++kt) {
    const int cur = kt & 1;
    // barrier 1: everyone done reading buf[cur^1] -> safe to overwrite
    asm volatile("s_waitcnt lgkmcnt(0)" ::: "memory");
    __builtin_amdgcn_s_barrier();
    if (kt < 31) {
      char* kd = klds + (cur ^ 1) * 8192 + w * 2048;
      char* vd = vlds + (cur ^ 1) * 8192 + w * 2048;
      const char* ks = ksrc0 + (size_t)(kt + 1) * 8192;
      const char* vs = vsrc0 + (kt + 1) * 128;
      async16(kd, ks);
      async16(kd + 1024, ks + 1024);
      async16(vd, vs);
      async16(vd + 1024, vs + 8 * 4096);
      asm volatile("s_waitcnt vmcnt(4)" ::: "memory");  // tile kt done; kt+1 in flight
    } else {
      asm volatile("s_waitcnt vmcnt(0)" ::: "memory");
    }
    __builtin_amdgcn_s_barrier();  // buf[cur] visible to all waves
    __builtin_amdgcn_sched_barrier(0);

    const char* kb = klds + cur * 8192;
    const char* vb = vlds + cur * 8192;

    // QK^T swapped: A = K rows, B = Q. D[key][q]: q=lr (per 16-group), key=kf*16+lg*4+i.
#pragma unroll
    for (int kf = 0; kf < 4; ++kf) {
      const char* ka = kb + (kf * 16 + lr) * 128;
      short8 a0 = *(const short8*)(ka + ((lg * 16) ^ psz));
      short8 a1 = *(const short8*)(ka + ((64 + lg * 16) ^ psz));
      f32x4 m4 = *(const f32x4*)(mrow + kt * 64 + kf * 16 + lg * 4);
#pragma unroll
      for (int qc = 0; qc < 2; ++qc) {
        f32x4 s = MFMA16(a0, aq[qc][0], fzero);
        s = MFMA16(a1, aq[qc][1], s);
        f32x4 ps;
#pragma unroll
        for (int i = 0; i < 4; ++i)
          ps[i] = __builtin_amdgcn_exp2f(fmaf(m4[i], LOG2E, s[i]));
        lsum[qc] += ps;
        unsigned w0, w1;
        asm("v_cvt_pk_bf16_f32 %0, %1, %2" : "=v"(w0) : "v"(ps[0]), "v"(ps[1]));
        asm("v_cvt_pk_bf16_f32 %0, %1, %2" : "=v"(w1) : "v"(ps[2]), "v"(ps[3]));
        uint2v pw2 = {w0, w1};
        *(uint2v*)(pl + (qc * 16 + lr) * 128 + ((kf * 32 + lg * 8) ^ psz)) = pw2;
      }
    }

    // PV: A = P[q][key], B = V^T[d][key]  (same-wave LDS RAW; compiler waits)
    short8 pa[2][2];
#pragma unroll
    for (int qc = 0; qc < 2; ++qc) {
      pa[qc][0] = *(const short8*)(pl + (qc * 16 + lr) * 128 + ((lg * 16) ^ psz));
      pa[qc][1] = *(const short8*)(pl + (qc * 16 + lr) * 128 + ((64 + lg * 16) ^ psz));
    }
    __builtin_amdgcn_s_setprio(1);
#pragma unroll
    for (int vf = 0; vf < 4; ++vf) {
      const char* vrow = vb + (vf * 16 + lr) * 128;
      short8 v0 = *(const short8*)(vrow + ((lg * 16) ^ psz));
      short8 v1 = *(const short8*)(vrow + ((64 + lg * 16) ^ psz));
#pragma unroll
      for (int qc = 0; qc < 2; ++qc) {
        o[qc][vf] = MFMA16(pa[qc][0], v0, o[qc][vf]);
        o[qc][vf] = MFMA16(pa[qc][1], v1, o[qc][vf]);
      }
    }
    __builtin_amdgcn_s_setprio(0);
  }

  // final sum reduce (deferred): lane-local 4 -> cross-lg -> broadcast to O layout
#pragma unroll
  for (int qc = 0; qc < 2; ++qc) {
    float lrun = (lsum[qc][0] + lsum[qc][1]) + (lsum[qc][2] + lsum[qc][3]);
    lrun += __shfl_xor(lrun, 16);
    lrun += __shfl_xor(lrun, 32);
    if (lg == 0) sbuf[qc * 16 + lr] = lrun;
  }
#pragma unroll
  for (int qc = 0; qc < 2; ++qc) {
    f32x4 l4 = *(const f32x4*)(sbuf + qc * 16 + lg * 4);
    f32x4 inv4;
#pragma unroll
    for (int i = 0; i < 4; ++i) inv4[i] = 1.0f / l4[i];
#pragma unroll
    for (int vf = 0; vf < 4; ++vf)
#pragma unroll
      for (int i = 0; i < 4; ++i)
        out[((size_t)bb * 2048 + q0 + w * 32 + qc * 16 + lg * 4 + i) * 1024 + hh * 64 +
            vf * 16 + lr] = o[qc][vf][i] * inv4[i];
  }
}

extern "C" void kernel_launch(void* const* d_in, const int* in_sizes, int n_in,
                              void* d_out, int out_size, void* d_ws, size_t ws_size,
                              hipStream_t stream) {
  const float* hs  = (const float*)d_in[0];
  const float* msk = (const float*)d_in[1];
  const float* Wq  = (const float*)d_in[2];
  const float* bq  = (const float*)d_in[3];
  const float* Wk  = (const float*)d_in[4];
  const float* bk  = (const float*)d_in[5];
  const float* Wv  = (const float*)d_in[6];
  const float* bv  = (const float*)d_in[7];
  float* out = (float*)d_out;
  char* ws = (char*)d_ws;
  ushort_t* Xb = (ushort_t*)ws;
  ushort_t* Wt = (ushort_t*)(ws + (16u << 20));
  ushort_t* Qb = (ushort_t*)(ws + (22u << 20));
  ushort_t* Kb = (ushort_t*)(ws + (38u << 20));
  ushort_t* Vt = (ushort_t*)(ws + (54u << 20));

  convert_x<<<4096, 256, 0, stream>>>(hs, Xb);
  convert_w<<<dim3(16, 16, 3), 256, 0, stream>>>(Wq, Wk, Wv, Wt);
  gemm_qkv<<<dim3(64, 24), 256, 0, stream>>>(Xb, Wt, bq, bk, bv, Qb, Kb, Vt);
  attn_fwd<<<dim3(16, 64), 256, 0, stream>>>(Qb, Kb, Vt, msk, out);
}

// Round 7
// 251.808 us; speedup vs baseline: 2.4331x; 1.1082x over previous
//
#include <hip/hip_runtime.h>
#include <hip/hip_bf16.h>
#include <stdint.h>

// BERT self-attention fwd: B=4,S=2048,H=1024,NH=16,HD=64. fp32 in/out, bf16 MFMA compute.
// ws layout: Xb bf16[8192][1024] @0 (16MB) | Wt bf16[3072][1024] @16MB (6MB)
//            Qb bf16[64][2048][64] @22MB (Q pre-scaled by log2e/8) | Kb @38MB | Vt bf16[64][64][2048] @54MB

typedef unsigned short ushort_t;
typedef __attribute__((ext_vector_type(4))) float f32x4;
typedef __attribute__((ext_vector_type(16))) float f32x16;
typedef __attribute__((ext_vector_type(8))) short short8;

#define MFMA16(a, b, c) __builtin_amdgcn_mfma_f32_16x16x32_bf16((a), (b), (c), 0, 0, 0)
#define MFMA32(a, b, c) __builtin_amdgcn_mfma_f32_32x32x16_bf16((a), (b), (c), 0, 0, 0)

__device__ __forceinline__ ushort_t f2bf(float f) {
  unsigned u = __float_as_uint(f);
  u = (u + 0x7FFFu + ((u >> 16) & 1u)) >> 16;
  return (ushort_t)u;
}

typedef __attribute__((address_space(1))) unsigned int as1_uint;
typedef __attribute__((address_space(3))) unsigned int as3_uint;

// async global->LDS, 16B per lane; lds_dst wave-uniform base (lane writes base + lane*16)
__device__ __forceinline__ void async16(void* lds_dst, const void* g_src) {
  __builtin_amdgcn_global_load_lds((as1_uint*)(uintptr_t)g_src,
                                   (as3_uint*)(unsigned)(uintptr_t)lds_dst, 16, 0, 0);
}

// ---------------- convert X fp32 -> bf16 ----------------
__global__ __launch_bounds__(256) void convert_x(const float* __restrict__ X,
                                                 ushort_t* __restrict__ Xb) {
  int idx = (blockIdx.x * 256 + threadIdx.x) * 8;
  f32x4 a = *(const f32x4*)(X + idx);
  f32x4 b = *(const f32x4*)(X + idx + 4);
  short8 r;
#pragma unroll
  for (int j = 0; j < 4; ++j) r[j] = (short)f2bf(a[j]);
#pragma unroll
  for (int j = 0; j < 4; ++j) r[4 + j] = (short)f2bf(b[j]);
  *(short8*)(Xb + idx) = r;
}

// ---------------- convert + transpose W -> Wt[n][k] bf16, 3 mats stacked ----------------
__global__ __launch_bounds__(256) void convert_w(const float* __restrict__ Wq,
                                                 const float* __restrict__ Wk,
                                                 const float* __restrict__ Wv,
                                                 ushort_t* __restrict__ Wt) {
  const int mat = blockIdx.z;
  const float* W = (mat == 0) ? Wq : ((mat == 1) ? Wk : Wv);
  const int k0 = blockIdx.x * 64, n0 = blockIdx.y * 64;
  __shared__ float t[64][65];
  const int tid = threadIdx.x;
#pragma unroll
  for (int it = 0; it < 16; ++it) {
    int idx = it * 256 + tid;
    int r = idx >> 6, c = idx & 63;
    t[r][c] = W[(size_t)(k0 + r) * 1024 + n0 + c];
  }
  __syncthreads();
#pragma unroll
  for (int it = 0; it < 16; ++it) {
    int idx = it * 256 + tid;
    int nr = idx >> 6, kc = idx & 63;
    Wt[(size_t)(mat * 1024 + n0 + nr) * 1024 + k0 + kc] = f2bf(t[kc][nr]);
  }
}

// ---------------- fused QKV GEMM: C[8192][3072] = Xb @ W, epilogue scatters to Q/K/Vt ----------------
__global__ __launch_bounds__(256) void gemm_qkv(const ushort_t* __restrict__ Xb,
                                                const ushort_t* __restrict__ Wt,
                                                const float* __restrict__ bq,
                                                const float* __restrict__ bk,
                                                const float* __restrict__ bv,
                                                ushort_t* __restrict__ Qb,
                                                ushort_t* __restrict__ Kb,
                                                ushort_t* __restrict__ Vt) {
  __shared__ char lds[36864];  // A 16KB @0, B 16KB @16384; epilogue V-transpose 4*9216
  const int tid = threadIdx.x;
  const int l = tid & 63, w = tid >> 6;
  const int m0 = blockIdx.x * 128;
  const int n0 = blockIdx.y * 128;
  const int wm = w >> 1, wn = w & 1;

  const int lr = l >> 3;
  const int kb_log = (((l & 7) ^ lr) << 4);
  const char* srcA = (const char*)Xb + (size_t)(m0 + w * 32 + lr) * 2048 + kb_log;
  const char* srcB = (const char*)Wt + (size_t)(n0 + w * 32 + lr) * 2048 + kb_log;
  char* ldsA_w = lds + w * 4096;
  char* ldsB_w = lds + 16384 + w * 4096;

  const int ra = wm * 64 + (l & 15);
  const int rb = wn * 64 + (l & 15);
  const int swz = (l & 7) << 4;
  const int x0 = (((l >> 4) << 4)) ^ swz;
  const int x1 = (64 + ((l >> 4) << 4)) ^ swz;

  f32x4 acc[4][4];
#pragma unroll
  for (int mf = 0; mf < 4; ++mf)
#pragma unroll
    for (int nf = 0; nf < 4; ++nf) acc[mf][nf] = (f32x4){0.f, 0.f, 0.f, 0.f};

#pragma unroll 1
  for (int kt = 0; kt < 16; ++kt) {
    if (kt) __syncthreads();
    const int koff = kt * 128;
#pragma unroll
    for (int c = 0; c < 4; ++c) {
      async16(ldsA_w + c * 1024, srcA + c * 16384 + koff);
      async16(ldsB_w + c * 1024, srcB + c * 16384 + koff);
    }
    __syncthreads();
#pragma unroll
    for (int half = 0; half < 2; ++half) {
      const int xo = half ? x1 : x0;
      short8 av[4], bv2[4];
#pragma unroll
      for (int mf = 0; mf < 4; ++mf)
        av[mf] = *(const short8*)(lds + (ra + mf * 16) * 128 + xo);
#pragma unroll
      for (int nf = 0; nf < 4; ++nf)
        bv2[nf] = *(const short8*)(lds + 16384 + (rb + nf * 16) * 128 + xo);
#pragma unroll
      for (int mf = 0; mf < 4; ++mf)
#pragma unroll
        for (int nf = 0; nf < 4; ++nf)
          acc[mf][nf] = MFMA16(av[mf], bv2[nf], acc[mf][nf]);
    }
  }

  __syncthreads();
  // epilogue
  const int col0 = n0 + wn * 64;
  const int mat = col0 >> 10;
  const int nn0 = col0 & 1023;
  const int hh = nn0 >> 6;
  const int row0 = m0 + wm * 64;
  const int bb = row0 >> 11;
  const int s0 = row0 & 2047;
  const float* bias = (mat == 0) ? bq : ((mat == 1) ? bk : bv);
  const float qscale = 0.18033688011112042f;  // log2(e)/sqrt(64), folded into Q
  if (mat < 2) {
    ushort_t* dst = (mat == 0) ? Qb : Kb;
    const float scl = (mat == 0) ? qscale : 1.0f;
#pragma unroll
    for (int mf = 0; mf < 4; ++mf)
#pragma unroll
      for (int nf = 0; nf < 4; ++nf)
#pragma unroll
        for (int i = 0; i < 4; ++i) {
          int r = mf * 16 + (l >> 4) * 4 + i;
          int d = nf * 16 + (l & 15);
          float v = (acc[mf][nf][i] + bias[nn0 + d]) * scl;
          dst[((size_t)(bb * 16 + hh) * 2048 + (s0 + r)) * 64 + d] = f2bf(v);
        }
  } else {
    ushort_t* vw = (ushort_t*)(lds + w * 9216);
#pragma unroll
    for (int mf = 0; mf < 4; ++mf)
#pragma unroll
      for (int nf = 0; nf < 4; ++nf)
#pragma unroll
        for (int i = 0; i < 4; ++i) {
          int r = mf * 16 + (l >> 4) * 4 + i;
          int d = nf * 16 + (l & 15);
          float v = acc[mf][nf][i] + bias[nn0 + d];
          vw[d * 72 + r] = f2bf(v);
        }
#pragma unroll
    for (int it = 0; it < 8; ++it) {
      int dr = it * 8 + (l >> 3);
      int sc = (l & 7) * 8;
      short8 vv = *(const short8*)((const char*)vw + dr * 144 + sc * 2);
      *(short8*)((char*)Vt + (((size_t)(bb * 16 + hh) * 64 + dr) * 2048 + s0 + sc) * 2) = vv;
    }
  }
}

// ---------------- flash attention fwd: 32x32 MFMA, in-register P via shfl_xor(32) ----------------
// grid (16, 64): x = q-tile (128 rows), y = b*16+h. 4 waves x 32 q-rows. KVBLK=64.
// LDS: klds 2x8KB @0 | vlds 2x8KB @16384 | sbuf 4x128B @32768
__global__ __launch_bounds__(256, 4) void attn_fwd(const ushort_t* __restrict__ Qb,
                                                   const ushort_t* __restrict__ Kb,
                                                   const ushort_t* __restrict__ Vt,
                                                   const float* __restrict__ mask,
                                                   float* __restrict__ out) {
  __shared__ char lds[33280];
  const int tid = threadIdx.x, l = tid & 63, w = tid >> 6;
  const int bh = blockIdx.y;
  const int bb = bh >> 4, hh = bh & 15;
  const int q0 = blockIdx.x * 128;
  const int l31 = l & 31, hi = l >> 5;
  char* klds = lds;
  char* vlds = lds + 16384;
  float* sbuf = (float*)(lds + 32768) + w * 32;

  const float LOG2E = 1.44269504088896340736f;
  const int psz = (l & 7) << 4;  // XOR swizzle; row&7 == l&7 for all read rows

  // Q B-frags (pre-scaled by log2e/8): col=q=l31, chunk c: k(d) = c*16 + hi*8 + j
  const char* qrow = (const char*)Qb + ((size_t)bh * 2048 + q0 + w * 32 + l31) * 128 + hi * 16;
  short8 qf[4];
#pragma unroll
  for (int c = 0; c < 4; ++c) qf[c] = *(const short8*)(qrow + c * 32);

  // staging sources (inverse-swizzled global col so linear LDS dest + swizzled reads agree)
  const int srow = l >> 3;
  const int scol = ((l & 7) ^ srow) << 4;
  const char* ksrc0 = (const char*)Kb + (size_t)bh * 2048 * 128 + (size_t)(w * 16 + srow) * 128 + scol;
  const char* vsrc0 = (const char*)Vt + ((size_t)bh * 64 + w * 16 + srow) * 4096 + scol;

  // prologue: stage tile 0 into buf 0
  {
    char* kd = klds + w * 2048;
    char* vd = vlds + w * 2048;
    async16(kd, ksrc0);
    async16(kd + 1024, ksrc0 + 1024);
    async16(vd, vsrc0);
    async16(vd + 1024, vsrc0 + 8 * 4096);
  }

  const float* mrow = mask + (size_t)bb * 2048;

  f32x16 o0, o1;
#pragma unroll
  for (int i = 0; i < 16; ++i) { o0[i] = 0.f; o1[i] = 0.f; }
  f32x4 lsum4 = (f32x4){0.f, 0.f, 0.f, 0.f};

#pragma unroll 1
  for (int kt = 0; kt < 32; ++kt) {
    const int cur = kt & 1;
    // everyone done reading buf[cur^1] -> safe to overwrite
    asm volatile("s_waitcnt lgkmcnt(0)" ::: "memory");
    __builtin_amdgcn_s_barrier();
    __builtin_amdgcn_sched_barrier(0);
    if (kt < 31) {
      char* kd = klds + (cur ^ 1) * 8192 + w * 2048;
      char* vd = vlds + (cur ^ 1) * 8192 + w * 2048;
      const char* ks = ksrc0 + (size_t)(kt + 1) * 8192;
      const char* vs = vsrc0 + (kt + 1) * 128;
      async16(kd, ks);
      async16(kd + 1024, ks + 1024);
      async16(vd, vs);
      async16(vd + 1024, vs + 8 * 4096);
      asm volatile("s_waitcnt vmcnt(4)" ::: "memory");  // tile kt landed; kt+1 in flight
    } else {
      asm volatile("s_waitcnt vmcnt(0)" ::: "memory");
    }
    __builtin_amdgcn_s_barrier();  // buf[cur] visible to all waves
    __builtin_amdgcn_sched_barrier(0);

    const char* kbuf = klds + cur * 8192;
    const char* vbuf = vlds + cur * 8192;

#pragma unroll
    for (int kb = 0; kb < 2; ++kb) {
      // QK^T swapped: A = K rows (key=l31 within kb block), B = Q (col=q=l31)
      // D[key][q]: q=l31, key_local = (reg&3) + 8*(reg>>2) + 4*hi
      f32x16 s;
#pragma unroll
      for (int i = 0; i < 16; ++i) s[i] = 0.f;
#pragma unroll
      for (int c = 0; c < 4; ++c) {
        short8 kf = *(const short8*)(kbuf + (kb * 32 + l31) * 128 + ((c * 32 + hi * 16) ^ psz));
        s = MFMA32(kf, qf[c], s);
      }
      // static-max softmax in log2 domain: p = exp2(s + mask*log2e)
      f32x16 pp;
#pragma unroll
      for (int r2 = 0; r2 < 4; ++r2) {
        f32x4 m4 = *(const f32x4*)(mrow + kt * 64 + kb * 32 + 8 * r2 + 4 * hi);
#pragma unroll
        for (int i = 0; i < 4; ++i)
          pp[4 * r2 + i] = __builtin_amdgcn_exp2f(fmaf(m4[i], LOG2E, s[4 * r2 + i]));
      }
#pragma unroll
      for (int i = 0; i < 4; ++i)
        lsum4[i] += ((pp[i] + pp[4 + i]) + (pp[8 + i] + pp[12 + i]));

      // P -> bf16 A-frags in-register.
      // u[2*r2+p] = pack(keys 8r2+4hi+2p, +1). pa[c] word w must hold keys 16c+8hi+2w,+1.
      // Cross-half exchange via shfl_xor(32): hi=0 sends u[4c+2{,+1}], hi=1 sends u[4c{,+1}].
      unsigned u[8];
#pragma unroll
      for (int r2 = 0; r2 < 4; ++r2) {
        asm("v_cvt_pk_bf16_f32 %0, %1, %2"
            : "=v"(u[2 * r2]) : "v"(pp[4 * r2]), "v"(pp[4 * r2 + 1]));
        asm("v_cvt_pk_bf16_f32 %0, %1, %2"
            : "=v"(u[2 * r2 + 1]) : "v"(pp[4 * r2 + 2]), "v"(pp[4 * r2 + 3]));
      }
      short8 pa[2];
#pragma unroll
      for (int c = 0; c < 2; ++c) {
        unsigned a0 = u[4 * c], b0 = u[4 * c + 2];
        unsigned a1 = u[4 * c + 1], b1 = u[4 * c + 3];
        unsigned s0 = hi ? a0 : b0;
        unsigned s1 = hi ? a1 : b1;
        unsigned r0 = (unsigned)__shfl_xor((int)s0, 32);
        unsigned r1 = (unsigned)__shfl_xor((int)s1, 32);
        union { unsigned uu[4]; short8 s8; } cv;
        cv.uu[0] = hi ? r0 : a0;  // word0: keys 16c+8hi+0,1
        cv.uu[1] = hi ? r1 : a1;  // word1: keys 16c+8hi+2,3
        cv.uu[2] = hi ? b0 : r0;  // word2: keys 16c+8hi+4,5
        cv.uu[3] = hi ? b1 : r1;  // word3: keys 16c+8hi+6,7
        pa[c] = cv.s8;
      }

      // PV for this key-block: A = P[q][key], B = V^T[d][key]; D col=d, row=q
      __builtin_amdgcn_s_setprio(1);
#pragma unroll
      for (int c = 0; c < 2; ++c) {
        const int koff = (kb * 64 + c * 32 + hi * 16) ^ psz;
        short8 v0 = *(const short8*)(vbuf + l31 * 128 + koff);
        short8 v1 = *(const short8*)(vbuf + (32 + l31) * 128 + koff);
        o0 = MFMA32(pa[c], v0, o0);
        o1 = MFMA32(pa[c], v1, o1);
      }
      __builtin_amdgcn_s_setprio(0);
    }
  }

  // epilogue: cross-half sum via shfl_xor(32), invert, redistribute to O layout
  float ls = (lsum4[0] + lsum4[1]) + (lsum4[2] + lsum4[3]);
  float other = __shfl_xor(ls, 32);
  float inv = 1.0f / (ls + other);
  if (hi == 0) sbuf[l31] = inv;
  float* obase = out + ((size_t)bb * 2048 + q0 + w * 32) * 1024 + hh * 64;
#pragma unroll
  for (int r2 = 0; r2 < 4; ++r2) {
    f32x4 iv = *(const f32x4*)(sbuf + 8 * r2 + 4 * hi);
#pragma unroll
    for (int r0 = 0; r0 < 4; ++r0) {
      const int q = 8 * r2 + 4 * hi + r0;
      obase[(size_t)q * 1024 + l31] = o0[4 * r2 + r0] * iv[r0];
      obase[(size_t)q * 1024 + 32 + l31] = o1[4 * r2 + r0] * iv[r0];
    }
  }
}

extern "C" void kernel_launch(void* const* d_in, const int* in_sizes, int n_in,
                              void* d_out, int out_size, void* d_ws, size_t ws_size,
                              hipStream_t stream) {
  const float* hs  = (const float*)d_in[0];
  const float* msk = (const float*)d_in[1];
  const float* Wq  = (const float*)d_in[2];
  const float* bq  = (const float*)d_in[3];
  const float* Wk  = (const float*)d_in[4];
  const float* bk  = (const float*)d_in[5];
  const float* Wv  = (const float*)d_in[6];
  const float* bv  = (const float*)d_in[7];
  float* out = (float*)d_out;
  char* ws = (char*)d_ws;
  ushort_t* Xb = (ushort_t*)ws;
  ushort_t* Wt = (ushort_t*)(ws + (16u << 20));
  ushort_t* Qb = (ushort_t*)(ws + (22u << 20));
  ushort_t* Kb = (ushort_t*)(ws + (38u << 20));
  ushort_t* Vt = (ushort_t*)(ws + (54u << 20));

  convert_x<<<4096, 256, 0, stream>>>(hs, Xb);
  convert_w<<<dim3(16, 16, 3), 256, 0, stream>>>(Wq, Wk, Wv, Wt);
  gemm_qkv<<<dim3(64, 24), 256, 0, stream>>>(Xb, Wt, bq, bk, bv, Qb, Kb, Vt);
  attn_fwd<<<dim3(16, 64), 256, 0, stream>>>(Qb, Kb, Vt, msk, out);
}